// Round 11
// baseline (380.169 us; speedup 1.0000x reference)
//
#include <hip/hip_runtime.h>
#include <cstddef>
#include <cstdint>

#define B_DIM 8
#define T_SEQ 4096
#define C_DIM 768
#define M_ROWS (B_DIM * T_SEQ)   // 32768
#define CC (C_DIM * C_DIM)       // 589824
#define NCH 32
#define CHL (T_SEQ / NCH)        // 128

using bf16x8 = __attribute__((ext_vector_type(8))) short;
using f32x4  = __attribute__((ext_vector_type(4))) float;

static __device__ __forceinline__ unsigned short f2bf(float f) {
  unsigned int u = __float_as_uint(f);
  return (unsigned short)((u + 0x7fffu + ((u >> 16) & 1u)) >> 16);
}
static __device__ __forceinline__ float bf2f(unsigned short s) {
  return __uint_as_float(((unsigned int)s) << 16);
}

static __device__ __forceinline__ void gload_lds16(const void* g, void* l) {
  __builtin_amdgcn_global_load_lds(
      (const __attribute__((address_space(1))) unsigned int*)g,
      (__attribute__((address_space(3))) unsigned int*)l, 16, 0, 0);
}

// ---------------------------------------------------------------------------
// f32 -> bf16 converts.
// ---------------------------------------------------------------------------
__global__ __launch_bounds__(256) void convert_x(
    const float4* __restrict__ x, ushort4* __restrict__ xh)
{
  int i = blockIdx.x * 256 + threadIdx.x;
  float4 v = x[i];
  ushort4 h;
  h.x = f2bf(v.x); h.y = f2bf(v.y); h.z = f2bf(v.z); h.w = f2bf(v.w);
  xh[i] = h;
}

__global__ __launch_bounds__(256) void convert_w4(
    const float4* __restrict__ w0, const float4* __restrict__ w1,
    const float4* __restrict__ w2, const float4* __restrict__ w3,
    ushort4* __restrict__ dst)
{
  const int z = blockIdx.y;
  const float4* __restrict__ src = (z == 0) ? w0 : (z == 1) ? w1 : (z == 2) ? w2 : w3;
  int i = blockIdx.x * 256 + threadIdx.x;
  float4 v = src[i];
  ushort4 h;
  h.x = f2bf(v.x); h.y = f2bf(v.y); h.z = f2bf(v.z); h.w = f2bf(v.w);
  dst[(size_t)z * (CC / 4) + i] = h;
}

// ---------------------------------------------------------------------------
// Prefetch-pipelined 256x256 MFMA GEMM (NT), K=768, BK=64, 8 waves (2M x 4N).
// R9's sector-coalesced staging + swizzled LDS kept. NEW: register frag
// ping-pong (X/Y): during MFMA of phase p, issue the 12 ds_reads of phase
// p+1 (different LDS region, already staged & drained) -> LDS reads overlap
// MFMA instead of serializing. Region protocol: region r = 2*tile + kh
// (16KB), 4 rotating slots; STG(r) issued at phase r-3; checkpoint vmcnt(4)
// at phase END drains region p+2, then barrier, then phase p+1 reads it
// (drain-before-barrier-before-read => cross-wave safe). Prologue stages
// r=0,1,2, vmcnt(4) drains r=0,1; tail CKPT(21)=vmcnt(0).
// Compiler emits counted lgkmcnt for MFMA deps (prefetch stays in flight).
// MODE 0: fused kvr, N=2304 over [Wk|Wv|Wr]; bf16 outs K/V/sigmoid->SR.
// MODE 1: out-GEMM, N=768, f32 out.
// ---------------------------------------------------------------------------
#define STG_A(DB, TAU, KH) do {                                            \
    const int ko_ = (TAU) * 64 + (KH) * 32;                                \
    short* d_ = lds + (((DB) + (KH) * 16384 + wave * 1024) >> 1);          \
    gload_lds16(pA_h0 + ko_, d_);                                          \
    gload_lds16(pA_h1 + ko_, d_ + 4096);                                   \
  } while (0)
#define STG_B(DB, TAU, KH) do {                                            \
    const int ko_ = (TAU) * 64 + (KH) * 32;                                \
    short* d_ = lds + (((DB) + 32768 + (KH) * 16384 + wave * 1024) >> 1);  \
    gload_lds16(pW_h0 + ko_, d_);                                          \
    gload_lds16(pW_h1 + ko_, d_ + 4096);                                   \
  } while (0)
#define STG_R(R) do {                                                      \
    STG_A((((R) >> 1) & 1) * 65536, (R) >> 1, (R) & 1);                    \
    STG_B((((R) >> 1) & 1) * 65536, (R) >> 1, (R) & 1);                    \
  } while (0)

#define READF(AA, BB, R) do {                                              \
    const int db_ = (((R) >> 1) & 1) * 65536 + ((R) & 1) * 16384;          \
    _Pragma("unroll")                                                      \
    for (int mi = 0; mi < 8; ++mi)                                         \
      AA[mi] = *(const bf16x8*)(lds + ((db_ + aoff + mi * 1024) >> 1));    \
    _Pragma("unroll")                                                      \
    for (int ni = 0; ni < 4; ++ni)                                         \
      BB[ni] = *(const bf16x8*)(lds + ((db_ + 32768 + boff + ni * 1024) >> 1)); \
  } while (0)

#define MM(AA, BB)                                                         \
    _Pragma("unroll")                                                      \
    for (int mi = 0; mi < 8; ++mi)                                         \
      _Pragma("unroll")                                                    \
      for (int ni = 0; ni < 4; ++ni)                                       \
        acc[mi][ni] = __builtin_amdgcn_mfma_f32_16x16x32_bf16(             \
            AA[mi], BB[ni], acc[mi][ni], 0, 0, 0);

template<int MODE>
__global__ __launch_bounds__(512, 2) void gemmPF(
    const short* __restrict__ A, const short* __restrict__ Wb,
    unsigned short* __restrict__ OK, unsigned short* __restrict__ OV,
    unsigned short* __restrict__ OSR, float* __restrict__ Oout)
{
  extern __shared__ short lds[];   // 128 KB
  const int K = C_DIM;
  constexpr int NWN = (MODE == 0) ? 9 : 3;     // n-tiles
  constexpr int CPX = (MODE == 0) ? 144 : 48;  // blocks per XCD (bijective)

  int f  = blockIdx.x + blockIdx.y * NWN;
  int wg = (f & 7) * CPX + (f >> 3);
  const int n0 = (wg % NWN) * 256;
  const int m0 = (wg / NWN) * 256;

  const int tid  = threadIdx.x;
  const int lane = tid & 63, wave = tid >> 6;
  const int wr = wave >> 2, wc = wave & 3;   // 2M x 4N wave grid
  const int lr = lane & 15, lk = lane >> 4;

  // fragment swizzle (lane-constant): slot = lk ^ ((lr>>1)&3)
  const int aswz = lk ^ ((lr >> 1) & 3);
  const int aoff = wr * 8192 + lr * 64 + aswz * 16;
  const int boff = (wc >> 1) * 8192 + (wc & 1) * 4096 + lr * 64 + aswz * 16;

  // staging sources: 4 lanes per row, 64B contiguous (chunk-permuted).
  const int srow = wave * 16 + (lane >> 2);
  const int skq  = (lane & 3) ^ ((lane >> 3) & 3);
  const short* pA_h0 = A + (size_t)(m0 + srow) * K + skq * 8;
  const short* pA_h1 = pA_h0 + (size_t)128 * K;
  const short* pW_h0 = Wb + (size_t)(n0 + srow) * K + skq * 8;
  const short* pW_h1 = pW_h0 + (size_t)128 * K;

  f32x4 acc[8][4];
#pragma unroll
  for (int i = 0; i < 8; ++i)
#pragma unroll
    for (int j = 0; j < 4; ++j) acc[i][j] = (f32x4){0.f, 0.f, 0.f, 0.f};

  bf16x8 aX[8], bX[4], aY[8], bY[4];

  // Prologue: stage regions 0,1,2; drain r0,r1; barrier; pre-read r0 -> X.
  STG_R(0); STG_R(1); STG_R(2);
  asm volatile("s_waitcnt vmcnt(4)" ::: "memory");
  __builtin_amdgcn_s_barrier();
  __builtin_amdgcn_sched_barrier(0);
  READF(aX, bX, 0);
  __builtin_amdgcn_sched_barrier(0);

  // 24 phases (12 K-tiles x 2 halves). Phase p: MFMA on set(p), prefetch
  // reads of region p+1 into other set, STG region p+3, CKPT at end.
#pragma unroll
  for (int p = 0; p < 24; ++p) {
    if (p < 23) {
      if (p & 1) { READF(aX, bX, p + 1); } else { READF(aY, bY, p + 1); }
    }
    if (p <= 20) STG_R(p + 3);
    __builtin_amdgcn_sched_barrier(0);
    __builtin_amdgcn_s_setprio(1);
    if (p & 1) { MM(aY, bY) } else { MM(aX, bX) }
    __builtin_amdgcn_s_setprio(0);
    if (p <= 20)      { asm volatile("s_waitcnt vmcnt(4)" ::: "memory"); }
    else if (p == 21) { asm volatile("s_waitcnt vmcnt(0)" ::: "memory"); }
    __builtin_amdgcn_s_barrier();
    __builtin_amdgcn_sched_barrier(0);
  }

  // Epilogue
  if (MODE == 0) {
    const int which = n0 / 768;               // 0:K 1:V 2:SR (all bf16 out)
    const int nc = (n0 % 768) + wc * 64;
    unsigned short* __restrict__ D = (which == 0) ? OK : (which == 1) ? OV : OSR;
#pragma unroll
    for (int mi = 0; mi < 8; ++mi)
#pragma unroll
      for (int ni = 0; ni < 4; ++ni) {
        const int row = m0 + wr * 128 + mi * 16 + lk * 4;
        const int col = nc + ni * 16 + lr;
#pragma unroll
        for (int j = 0; j < 4; ++j) {
          float v = acc[mi][ni][j];
          if (which == 2) v = 1.f / (1.f + __expf(-v));
          D[(size_t)(row + j) * C_DIM + col] = f2bf(v);
        }
      }
  } else {
#pragma unroll
    for (int mi = 0; mi < 8; ++mi)
#pragma unroll
      for (int ni = 0; ni < 4; ++ni) {
        const int row = m0 + wr * 128 + mi * 16 + lk * 4;
        const int col = n0 + wc * 64 + ni * 16 + lr;
#pragma unroll
        for (int j = 0; j < 4; ++j)
          Oout[(size_t)(row + j) * C_DIM + col] = acc[mi][ni][j];
      }
  }
}

// ---------------------------------------------------------------------------
// WKV pass 1: per-(b,c,chunk) local transition triple (unchanged).
// ---------------------------------------------------------------------------
#define P1_LOAD(kk_, vv_, base_)                                  \
  _Pragma("unroll") for (int j = 0; j < 8; ++j) {                 \
    int r_ = si[(base_) + j];                                     \
    kk_[j] = Kb[(size_t)r_ * C_DIM];                              \
    vv_[j] = Vb[(size_t)r_ * C_DIM];                              \
  }
#define P1_COMP(kk_, vv_)                                         \
  _Pragma("unroll") for (int j = 0; j < 8; ++j) {                 \
    float kt = bf2f(kk_[j]), vt = bf2f(vv_[j]);                   \
    float ww2 = w + pp; float p2 = fmaxf(ww2, kt);                \
    float e1b = __expf(ww2 - p2), e2b = __expf(kt - p2);          \
    aa = e1b * aa + e2b * vt; bb = e1b * bb + e2b; pp = p2;       \
  }

__global__ __launch_bounds__(256) void wkv_pass1(
    const unsigned short* __restrict__ Kin, const unsigned short* __restrict__ Vin,
    const int* __restrict__ sidx, const float* __restrict__ decay,
    float* __restrict__ aL, float* __restrict__ bL, float* __restrict__ pL)
{
  __shared__ int si[CHL];
  const int tid = threadIdx.x;
  const int ch = blockIdx.x, b = blockIdx.z;
  const int c = blockIdx.y * 256 + tid;
  if (tid < CHL) si[tid] = sidx[ch * CHL + tid];
  __syncthreads();
  const float w = decay[c] * (1.0f / (float)T_SEQ);
  const unsigned short* Kb = Kin + (size_t)b * T_SEQ * C_DIM + c;
  const unsigned short* Vb = Vin + (size_t)b * T_SEQ * C_DIM + c;
  float aa = 0.f, bb = 0.f, pp = -1e38f;
  unsigned short kA[8], vA[8], kB[8], vB[8];
  P1_LOAD(kA, vA, 0)
  for (int t0 = 0; t0 < CHL; t0 += 16) {
    P1_LOAD(kB, vB, t0 + 8)
    P1_COMP(kA, vA)
    if (t0 + 16 < CHL) { P1_LOAD(kA, vA, t0 + 16) }
    P1_COMP(kB, vB)
  }
  const int idx = (b * C_DIM + c) * NCH + ch;
  aL[idx] = aa; bL[idx] = bb; pL[idx] = pp;
}

// Serial scan over chunks per (b,c).
__global__ __launch_bounds__(256) void wkv_scan(
    const float* __restrict__ aL, const float* __restrict__ bL,
    const float* __restrict__ pL,
    float* __restrict__ aI, float* __restrict__ bI, float* __restrict__ pI,
    const float* __restrict__ decay)
{
  const int g = blockIdx.x * 256 + threadIdx.x;  // 0..6143 = b*C + c
  const int c = g % C_DIM;
  const float wL = decay[c] * ((float)CHL / (float)T_SEQ);
  float aa = 0.f, bb = 0.f, pp = -1e38f;
  const int base = g * NCH;
  for (int ch = 0; ch < NCH; ++ch) {
    aI[base + ch] = aa; bI[base + ch] = bb; pI[base + ch] = pp;
    float p1 = pp + wL;
    float p2 = pL[base + ch];
    float p  = fmaxf(p1, p2);
    float e1 = __expf(p1 - p), e2 = __expf(p2 - p);
    aa = e1 * aa + e2 * aL[base + ch];
    bb = e1 * bb + e2 * bL[base + ch];
    pp = p;
  }
}

// ---------------------------------------------------------------------------
// Pass 2 FUSED with LayerNorm + gate: one 768-thread block per (chunk, b)
// holds the entire channel row at each timestep -> block-reduce mean/var,
// apply LN * sigmoid-gate, write G (bf16) directly. Y buffer eliminated;
// y stays f32 into LN (closer to reference). 1 barrier per timestep via
// parity-alternating reduction slots.
// ---------------------------------------------------------------------------
#define P2F_LOAD(rr_, kk_, vv_, ss_, base_)                       \
  _Pragma("unroll") for (int j = 0; j < 8; ++j) {                 \
    int r_ = si[(base_) + j];                                     \
    rr_[j] = r_;                                                  \
    kk_[j] = Kb[(size_t)r_ * C_DIM];                              \
    vv_[j] = Vb[(size_t)r_ * C_DIM];                              \
    ss_[j] = Sb[(size_t)r_ * C_DIM];                              \
  }

#define P2F_COMP(rr_, kk_, vv_, ss_)                              \
  _Pragma("unroll") for (int j = 0; j < 8; ++j) {                 \
    float kt = bf2f(kk_[j]), vt = bf2f(vv_[j]);                   \
    float ww = u + kt; float p = fmaxf(pp, ww);                   \
    float e1 = __expf(pp - p), e2 = __expf(ww - p);               \
    float y = (e1 * aa + e2 * vt) / (e1 * bbs + e2);              \
    float s1 = y, s2v = y * y;                                    \
    _Pragma("unroll")                                             \
    for (int off = 32; off >= 1; off >>= 1) {                     \
      s1  += __shfl_xor(s1, off, 64);                             \
      s2v += __shfl_xor(s2v, off, 64);                            \
    }                                                             \
    if (lane == 0) { red[j & 1][0][wid] = s1; red[j & 1][1][wid] = s2v; } \
    __syncthreads();                                              \
    float ts = 0.f, ts2 = 0.f;                                    \
    _Pragma("unroll")                                             \
    for (int wv = 0; wv < 12; ++wv) {                             \
      ts  += red[j & 1][0][wv];                                   \
      ts2 += red[j & 1][1][wv];                                   \
    }                                                             \
    const float mu  = ts * (1.f / (float)C_DIM);                  \
    const float var = ts2 * (1.f / (float)C_DIM) - mu * mu;       \
    const float rs  = rsqrtf(var + 1e-5f);                        \
    const float yln = (y - mu) * rs * gg + bb0;                   \
    Gb[(size_t)rr_[j] * C_DIM] = f2bf(yln * bf2f(ss_[j]));        \
    float ww2 = w + pp; float p2 = fmaxf(ww2, kt);                \
    float e1b = __expf(ww2 - p2), e2b = __expf(kt - p2);          \
    aa = e1b * aa + e2b * vt; bbs = e1b * bbs + e2b; pp = p2;     \
  }

__global__ __launch_bounds__(768) void wkv_pass2_ln(
    const unsigned short* __restrict__ Kin, const unsigned short* __restrict__ Vin,
    const int* __restrict__ sidx,
    const float* __restrict__ decay, const float* __restrict__ first,
    const float* __restrict__ aI, const float* __restrict__ bI,
    const float* __restrict__ pI,
    const unsigned short* __restrict__ SR,
    const float* __restrict__ gam, const float* __restrict__ bet,
    unsigned short* __restrict__ G)
{
  __shared__ int si[CHL];
  __shared__ float red[2][2][12];
  const int tid = threadIdx.x;          // = channel c
  const int ch = blockIdx.x, b = blockIdx.y;
  if (tid < CHL) si[tid] = sidx[ch * CHL + tid];
  __syncthreads();
  const int c = tid;
  const int lane = tid & 63, wid = tid >> 6;
  const float w = decay[c] * (1.0f / (float)T_SEQ);
  const float u = first[c] * (1.0f / (float)T_SEQ);
  const float gg = gam[c], bb0 = bet[c];
  const unsigned short* Kb = Kin + (size_t)b * T_SEQ * C_DIM + c;
  const unsigned short* Vb = Vin + (size_t)b * T_SEQ * C_DIM + c;
  const unsigned short* Sb = SR + (size_t)b * T_SEQ * C_DIM + c;
  unsigned short* Gb = G + (size_t)b * T_SEQ * C_DIM + c;
  const int idx = (b * C_DIM + c) * NCH + ch;
  float aa = aI[idx], bbs = bI[idx], pp = pI[idx];

  int rA[8], rB[8];
  unsigned short kA[8], vA[8], sA[8], kB[8], vB[8], sB[8];
  P2F_LOAD(rA, kA, vA, sA, 0)
  for (int t0 = 0; t0 < CHL; t0 += 16) {
    P2F_LOAD(rB, kB, vB, sB, t0 + 8)
    P2F_COMP(rA, kA, vA, sA)
    if (t0 + 16 < CHL) { P2F_LOAD(rA, kA, vA, sA, t0 + 16) }
    P2F_COMP(rB, kB, vB, sB)
  }
}

// ---------------------------------------------------------------------------
extern "C" void kernel_launch(void* const* d_in, const int* in_sizes, int n_in,
                              void* d_out, int out_size, void* d_ws, size_t ws_size,
                              hipStream_t stream) {
  const float* x     = (const float*)d_in[0];
  const int*   sidx  = (const int*)  d_in[1];
  const float* decay = (const float*)d_in[2];
  const float* first = (const float*)d_in[3];
  const float* Wk    = (const float*)d_in[4];
  const float* Wv    = (const float*)d_in[5];
  const float* Wr    = (const float*)d_in[6];
  const float* Wo    = (const float*)d_in[7];
  const float* ln_g  = (const float*)d_in[8];
  const float* ln_b  = (const float*)d_in[9];
  float* out = (float*)d_out;

  const size_t NE = (size_t)M_ROWS * C_DIM;  // 25165824
  // Workspace layout (~261 MB, no aliasing needed):
  short* Whs  = (short*)d_ws;                           // 4*CC bf16
  short* x_hi = Whs + 4 * (size_t)CC;                   // NE bf16
  unsigned short* Kbuf = (unsigned short*)(x_hi + NE);  // NE bf16
  unsigned short* Vbuf = Kbuf + NE;                     // NE bf16
  unsigned short* SRb  = Vbuf + NE;                     // NE bf16
  unsigned short* Gbuf = SRb + NE;                      // NE bf16 (own slot)
  float* aL = (float*)(Gbuf + NE);                      // 6 x 196608 f32
  float* bL = aL + 196608;
  float* pL = bL + 196608;
  float* aI = pL + 196608;
  float* bI = aI + 196608;
  float* pI = bI + 196608;

  // Allow 128 KB dynamic LDS (idempotent, capture-safe).
  (void)hipFuncSetAttribute(reinterpret_cast<const void*>(&gemmPF<0>),
                            hipFuncAttributeMaxDynamicSharedMemorySize, 131072);
  (void)hipFuncSetAttribute(reinterpret_cast<const void*>(&gemmPF<1>),
                            hipFuncAttributeMaxDynamicSharedMemorySize, 131072);

  // 1) bf16 conversions
  convert_x<<<24576, 256, 0, stream>>>((const float4*)x, (ushort4*)x_hi);
  convert_w4<<<dim3(576, 4), 256, 0, stream>>>(
      (const float4*)Wk, (const float4*)Wv, (const float4*)Wr, (const float4*)Wo,
      (ushort4*)Whs);

  // 2) fused k|v|sr GEMM: M=32768, N=2304, K=768; all outputs bf16
  gemmPF<0><<<dim3(9, 128), 512, 131072, stream>>>(
      x_hi, Whs, Kbuf, Vbuf, SRb, nullptr);

  // 3) WKV: chunk transitions -> serial chunk scan -> fused replay+LN+gate
  wkv_pass1<<<dim3(NCH, 3, B_DIM), 256, 0, stream>>>(Kbuf, Vbuf, sidx, decay, aL, bL, pL);
  wkv_scan<<<24, 256, 0, stream>>>(aL, bL, pL, aI, bI, pI, decay);
  wkv_pass2_ln<<<dim3(NCH, B_DIM), 768, 0, stream>>>(
      Kbuf, Vbuf, sidx, decay, first, aI, bI, pI, SRb, ln_g, ln_b, Gbuf);

  // 4) out = G @ Wo^T (384 blocks of 256^2, f32 out)
  gemmPF<1><<<dim3(3, 128), 512, 131072, stream>>>(
      (const short*)Gbuf, Whs + 3 * (size_t)CC, nullptr, nullptr, nullptr, out);
}

// Round 12
// 313.380 us; speedup vs baseline: 1.2131x; 1.2131x over previous
//
#include <hip/hip_runtime.h>
#include <cstddef>
#include <cstdint>

#define B_DIM 8
#define T_SEQ 4096
#define C_DIM 768
#define M_ROWS (B_DIM * T_SEQ)   // 32768
#define CC (C_DIM * C_DIM)       // 589824
#define NCH 32
#define CHL (T_SEQ / NCH)        // 128

using bf16x8 = __attribute__((ext_vector_type(8))) short;
using f32x4  = __attribute__((ext_vector_type(4))) float;

static __device__ __forceinline__ unsigned short f2bf(float f) {
  unsigned int u = __float_as_uint(f);
  return (unsigned short)((u + 0x7fffu + ((u >> 16) & 1u)) >> 16);
}
static __device__ __forceinline__ float bf2f(unsigned short s) {
  return __uint_as_float(((unsigned int)s) << 16);
}

static __device__ __forceinline__ void gload_lds16(const void* g, void* l) {
  __builtin_amdgcn_global_load_lds(
      (const __attribute__((address_space(1))) unsigned int*)g,
      (__attribute__((address_space(3))) unsigned int*)l, 16, 0, 0);
}

// ---------------------------------------------------------------------------
// f32 -> bf16 converts.
// ---------------------------------------------------------------------------
__global__ __launch_bounds__(256) void convert_x(
    const float4* __restrict__ x, ushort4* __restrict__ xh)
{
  int i = blockIdx.x * 256 + threadIdx.x;
  float4 v = x[i];
  ushort4 h;
  h.x = f2bf(v.x); h.y = f2bf(v.y); h.z = f2bf(v.z); h.w = f2bf(v.w);
  xh[i] = h;
}

__global__ __launch_bounds__(256) void convert_w4(
    const float4* __restrict__ w0, const float4* __restrict__ w1,
    const float4* __restrict__ w2, const float4* __restrict__ w3,
    ushort4* __restrict__ dst)
{
  const int z = blockIdx.y;
  const float4* __restrict__ src = (z == 0) ? w0 : (z == 1) ? w1 : (z == 2) ? w2 : w3;
  int i = blockIdx.x * 256 + threadIdx.x;
  float4 v = src[i];
  ushort4 h;
  h.x = f2bf(v.x); h.y = f2bf(v.y); h.z = f2bf(v.z); h.w = f2bf(v.w);
  dst[(size_t)z * (CC / 4) + i] = h;
}

// ---------------------------------------------------------------------------
// Prefetch-pipelined 256x256 MFMA GEMM (NT), K=768, BK=64, 8 waves (2M x 4N).
// Sector-coalesced staging (4 lanes/row, 64B/row, chunk swz, inverse on
// global source) + register frag ping-pong: during MFMA of phase p, issue
// the 12 ds_reads of phase p+1 (region already staged & drained). Region
// r = 2*tile + kh (16KB), 4 rotating slots; STG(r) at phase r-3; vmcnt(4)
// at phase END drains region p+2 before the barrier that precedes its
// readers. Prologue stages r=0,1,2; tail CKPT(21)=vmcnt(0).
// MODE 0: fused kvr, N=2304 over [Wk|Wv|Wr]; bf16 outs K/V/sigmoid->SR.
// MODE 1: out-GEMM, N=768, f32 out.  (Measured R11: 141us kvr, 36% MfmaUtil)
// ---------------------------------------------------------------------------
#define STG_A(DB, TAU, KH) do {                                            \
    const int ko_ = (TAU) * 64 + (KH) * 32;                                \
    short* d_ = lds + (((DB) + (KH) * 16384 + wave * 1024) >> 1);          \
    gload_lds16(pA_h0 + ko_, d_);                                          \
    gload_lds16(pA_h1 + ko_, d_ + 4096);                                   \
  } while (0)
#define STG_B(DB, TAU, KH) do {                                            \
    const int ko_ = (TAU) * 64 + (KH) * 32;                                \
    short* d_ = lds + (((DB) + 32768 + (KH) * 16384 + wave * 1024) >> 1);  \
    gload_lds16(pW_h0 + ko_, d_);                                          \
    gload_lds16(pW_h1 + ko_, d_ + 4096);                                   \
  } while (0)
#define STG_R(R) do {                                                      \
    STG_A((((R) >> 1) & 1) * 65536, (R) >> 1, (R) & 1);                    \
    STG_B((((R) >> 1) & 1) * 65536, (R) >> 1, (R) & 1);                    \
  } while (0)

#define READF(AA, BB, R) do {                                              \
    const int db_ = (((R) >> 1) & 1) * 65536 + ((R) & 1) * 16384;          \
    _Pragma("unroll")                                                      \
    for (int mi = 0; mi < 8; ++mi)                                         \
      AA[mi] = *(const bf16x8*)(lds + ((db_ + aoff + mi * 1024) >> 1));    \
    _Pragma("unroll")                                                      \
    for (int ni = 0; ni < 4; ++ni)                                         \
      BB[ni] = *(const bf16x8*)(lds + ((db_ + 32768 + boff + ni * 1024) >> 1)); \
  } while (0)

#define MM(AA, BB)                                                         \
    _Pragma("unroll")                                                      \
    for (int mi = 0; mi < 8; ++mi)                                         \
      _Pragma("unroll")                                                    \
      for (int ni = 0; ni < 4; ++ni)                                       \
        acc[mi][ni] = __builtin_amdgcn_mfma_f32_16x16x32_bf16(             \
            AA[mi], BB[ni], acc[mi][ni], 0, 0, 0);

template<int MODE>
__global__ __launch_bounds__(512, 2) void gemmPF(
    const short* __restrict__ A, const short* __restrict__ Wb,
    unsigned short* __restrict__ OK, unsigned short* __restrict__ OV,
    unsigned short* __restrict__ OSR, float* __restrict__ Oout)
{
  extern __shared__ short lds[];   // 128 KB
  const int K = C_DIM;
  constexpr int NWN = (MODE == 0) ? 9 : 3;     // n-tiles
  constexpr int CPX = (MODE == 0) ? 144 : 48;  // blocks per XCD (bijective)

  int f  = blockIdx.x + blockIdx.y * NWN;
  int wg = (f & 7) * CPX + (f >> 3);
  const int n0 = (wg % NWN) * 256;
  const int m0 = (wg / NWN) * 256;

  const int tid  = threadIdx.x;
  const int lane = tid & 63, wave = tid >> 6;
  const int wr = wave >> 2, wc = wave & 3;   // 2M x 4N wave grid
  const int lr = lane & 15, lk = lane >> 4;

  // fragment swizzle (lane-constant): slot = lk ^ ((lr>>1)&3)
  const int aswz = lk ^ ((lr >> 1) & 3);
  const int aoff = wr * 8192 + lr * 64 + aswz * 16;
  const int boff = (wc >> 1) * 8192 + (wc & 1) * 4096 + lr * 64 + aswz * 16;

  // staging sources: 4 lanes per row, 64B contiguous (chunk-permuted).
  const int srow = wave * 16 + (lane >> 2);
  const int skq  = (lane & 3) ^ ((lane >> 3) & 3);
  const short* pA_h0 = A + (size_t)(m0 + srow) * K + skq * 8;
  const short* pA_h1 = pA_h0 + (size_t)128 * K;
  const short* pW_h0 = Wb + (size_t)(n0 + srow) * K + skq * 8;
  const short* pW_h1 = pW_h0 + (size_t)128 * K;

  f32x4 acc[8][4];
#pragma unroll
  for (int i = 0; i < 8; ++i)
#pragma unroll
    for (int j = 0; j < 4; ++j) acc[i][j] = (f32x4){0.f, 0.f, 0.f, 0.f};

  bf16x8 aX[8], bX[4], aY[8], bY[4];

  // Prologue: stage regions 0,1,2; drain r0,r1; barrier; pre-read r0 -> X.
  STG_R(0); STG_R(1); STG_R(2);
  asm volatile("s_waitcnt vmcnt(4)" ::: "memory");
  __builtin_amdgcn_s_barrier();
  __builtin_amdgcn_sched_barrier(0);
  READF(aX, bX, 0);
  __builtin_amdgcn_sched_barrier(0);

  // 24 phases (12 K-tiles x 2 halves).
#pragma unroll
  for (int p = 0; p < 24; ++p) {
    if (p < 23) {
      if (p & 1) { READF(aX, bX, p + 1); } else { READF(aY, bY, p + 1); }
    }
    if (p <= 20) STG_R(p + 3);
    __builtin_amdgcn_sched_barrier(0);
    __builtin_amdgcn_s_setprio(1);
    if (p & 1) { MM(aY, bY) } else { MM(aX, bX) }
    __builtin_amdgcn_s_setprio(0);
    if (p <= 20)      { asm volatile("s_waitcnt vmcnt(4)" ::: "memory"); }
    else if (p == 21) { asm volatile("s_waitcnt vmcnt(0)" ::: "memory"); }
    __builtin_amdgcn_s_barrier();
    __builtin_amdgcn_sched_barrier(0);
  }

  // Epilogue
  if (MODE == 0) {
    const int which = n0 / 768;               // 0:K 1:V 2:SR (all bf16 out)
    const int nc = (n0 % 768) + wc * 64;
    unsigned short* __restrict__ D = (which == 0) ? OK : (which == 1) ? OV : OSR;
#pragma unroll
    for (int mi = 0; mi < 8; ++mi)
#pragma unroll
      for (int ni = 0; ni < 4; ++ni) {
        const int row = m0 + wr * 128 + mi * 16 + lk * 4;
        const int col = nc + ni * 16 + lr;
#pragma unroll
        for (int j = 0; j < 4; ++j) {
          float v = acc[mi][ni][j];
          if (which == 2) v = 1.f / (1.f + __expf(-v));
          D[(size_t)(row + j) * C_DIM + col] = f2bf(v);
        }
      }
  } else {
#pragma unroll
    for (int mi = 0; mi < 8; ++mi)
#pragma unroll
      for (int ni = 0; ni < 4; ++ni) {
        const int row = m0 + wr * 128 + mi * 16 + lk * 4;
        const int col = n0 + wc * 64 + ni * 16 + lr;
#pragma unroll
        for (int j = 0; j < 4; ++j)
          Oout[(size_t)(row + j) * C_DIM + col] = acc[mi][ni][j];
      }
  }
}

// ---------------------------------------------------------------------------
// WKV chunk-parallel scan over bf16 K/V (R9/R10 proven versions).
// ---------------------------------------------------------------------------
#define P1_LOAD(kk_, vv_, base_)                                  \
  _Pragma("unroll") for (int j = 0; j < 8; ++j) {                 \
    int r_ = si[(base_) + j];                                     \
    kk_[j] = Kb[(size_t)r_ * C_DIM];                              \
    vv_[j] = Vb[(size_t)r_ * C_DIM];                              \
  }
#define P1_COMP(kk_, vv_)                                         \
  _Pragma("unroll") for (int j = 0; j < 8; ++j) {                 \
    float kt = bf2f(kk_[j]), vt = bf2f(vv_[j]);                   \
    float ww2 = w + pp; float p2 = fmaxf(ww2, kt);                \
    float e1b = __expf(ww2 - p2), e2b = __expf(kt - p2);          \
    aa = e1b * aa + e2b * vt; bb = e1b * bb + e2b; pp = p2;       \
  }

__global__ __launch_bounds__(256) void wkv_pass1(
    const unsigned short* __restrict__ Kin, const unsigned short* __restrict__ Vin,
    const int* __restrict__ sidx, const float* __restrict__ decay,
    float* __restrict__ aL, float* __restrict__ bL, float* __restrict__ pL)
{
  __shared__ int si[CHL];
  const int tid = threadIdx.x;
  const int ch = blockIdx.x, b = blockIdx.z;
  const int c = blockIdx.y * 256 + tid;
  if (tid < CHL) si[tid] = sidx[ch * CHL + tid];
  __syncthreads();
  const float w = decay[c] * (1.0f / (float)T_SEQ);
  const unsigned short* Kb = Kin + (size_t)b * T_SEQ * C_DIM + c;
  const unsigned short* Vb = Vin + (size_t)b * T_SEQ * C_DIM + c;
  float aa = 0.f, bb = 0.f, pp = -1e38f;
  unsigned short kA[8], vA[8], kB[8], vB[8];
  P1_LOAD(kA, vA, 0)
  for (int t0 = 0; t0 < CHL; t0 += 16) {
    P1_LOAD(kB, vB, t0 + 8)
    P1_COMP(kA, vA)
    if (t0 + 16 < CHL) { P1_LOAD(kA, vA, t0 + 16) }
    P1_COMP(kB, vB)
  }
  const int idx = (b * C_DIM + c) * NCH + ch;
  aL[idx] = aa; bL[idx] = bb; pL[idx] = pp;
}

// Serial scan over chunks per (b,c).
__global__ __launch_bounds__(256) void wkv_scan(
    const float* __restrict__ aL, const float* __restrict__ bL,
    const float* __restrict__ pL,
    float* __restrict__ aI, float* __restrict__ bI, float* __restrict__ pI,
    const float* __restrict__ decay)
{
  const int g = blockIdx.x * 256 + threadIdx.x;  // 0..6143 = b*C + c
  const int c = g % C_DIM;
  const float wL = decay[c] * ((float)CHL / (float)T_SEQ);
  float aa = 0.f, bb = 0.f, pp = -1e38f;
  const int base = g * NCH;
  for (int ch = 0; ch < NCH; ++ch) {
    aI[base + ch] = aa; bI[base + ch] = bb; pI[base + ch] = pp;
    float p1 = pp + wL;
    float p2 = pL[base + ch];
    float p  = fmaxf(p1, p2);
    float e1 = __expf(p1 - p), e2 = __expf(p2 - p);
    aa = e1 * aa + e2 * aL[base + ch];
    bb = e1 * bb + e2 * bL[base + ch];
    pp = p;
  }
}

// Pass 2: replay chunk with incoming state; y (bf16) scattered to natural order.
#define P2_LOAD(rr_, kk_, vv_, base_)                             \
  _Pragma("unroll") for (int j = 0; j < 8; ++j) {                 \
    int r_ = si[(base_) + j];                                     \
    rr_[j] = r_;                                                  \
    kk_[j] = Kb[(size_t)r_ * C_DIM];                              \
    vv_[j] = Vb[(size_t)r_ * C_DIM];                              \
  }
#define P2_COMP(rr_, kk_, vv_)                                    \
  _Pragma("unroll") for (int j = 0; j < 8; ++j) {                 \
    float kt = bf2f(kk_[j]), vt = bf2f(vv_[j]);                   \
    float ww = u + kt; float p = fmaxf(pp, ww);                   \
    float e1 = __expf(pp - p), e2 = __expf(ww - p);               \
    float y = (e1 * aa + e2 * vt) / (e1 * bb + e2);               \
    Yb[(size_t)rr_[j] * C_DIM] = f2bf(y);                         \
    float ww2 = w + pp; float p2 = fmaxf(ww2, kt);                \
    float e1b = __expf(ww2 - p2), e2b = __expf(kt - p2);          \
    aa = e1b * aa + e2b * vt; bb = e1b * bb + e2b; pp = p2;       \
  }

__global__ __launch_bounds__(256) void wkv_pass2(
    const unsigned short* __restrict__ Kin, const unsigned short* __restrict__ Vin,
    const int* __restrict__ sidx,
    const float* __restrict__ decay, const float* __restrict__ first,
    const float* __restrict__ aI, const float* __restrict__ bI,
    const float* __restrict__ pI, unsigned short* __restrict__ Y)
{
  __shared__ int si[CHL];
  const int tid = threadIdx.x;
  const int ch = blockIdx.x, b = blockIdx.z;
  const int c = blockIdx.y * 256 + tid;
  if (tid < CHL) si[tid] = sidx[ch * CHL + tid];
  __syncthreads();
  const float w = decay[c] * (1.0f / (float)T_SEQ);
  const float u = first[c] * (1.0f / (float)T_SEQ);
  const unsigned short* Kb = Kin + (size_t)b * T_SEQ * C_DIM + c;
  const unsigned short* Vb = Vin + (size_t)b * T_SEQ * C_DIM + c;
  unsigned short* Yb = Y + (size_t)b * T_SEQ * C_DIM + c;
  const int idx = (b * C_DIM + c) * NCH + ch;
  float aa = aI[idx], bb = bI[idx], pp = pI[idx];
  int rA[8], rB[8]; unsigned short kA[8], vA[8], kB[8], vB[8];
  P2_LOAD(rA, kA, vA, 0)
  for (int t0 = 0; t0 < CHL; t0 += 16) {
    P2_LOAD(rB, kB, vB, t0 + 8)
    P2_COMP(rA, kA, vA)
    if (t0 + 16 < CHL) { P2_LOAD(rA, kA, vA, t0 + 16) }
    P2_COMP(rB, kB, vB)
  }
}

// ---------------------------------------------------------------------------
// Row LayerNorm over C + sigmoid gate; bf16 in (Y, SR), bf16 out (G).
// ---------------------------------------------------------------------------
__global__ __launch_bounds__(256) void ln_gate(
    const unsigned short* __restrict__ Y, const unsigned short* __restrict__ SR,
    const float* __restrict__ gam, const float* __restrict__ bet,
    unsigned short* __restrict__ G)
{
  const size_t row = blockIdx.x;
  const unsigned short* x = Y + row * C_DIM;
  const unsigned short* sr = SR + row * C_DIM;
  unsigned short* go = G + row * C_DIM;
  const int tid = threadIdx.x;

  float vals[3];
  float s = 0.f, s2 = 0.f;
#pragma unroll
  for (int j = 0; j < 3; ++j) {
    float v = bf2f(x[tid + j * 256]);
    vals[j] = v;
    s += v; s2 += v * v;
  }
#pragma unroll
  for (int off = 32; off >= 1; off >>= 1) {
    s  += __shfl_xor(s, off, 64);
    s2 += __shfl_xor(s2, off, 64);
  }
  __shared__ float red[8];
  const int wid = tid >> 6;
  if ((tid & 63) == 0) { red[wid] = s; red[wid + 4] = s2; }
  __syncthreads();
  s  = red[0] + red[1] + red[2] + red[3];
  s2 = red[4] + red[5] + red[6] + red[7];

  const float mu   = s * (1.f / (float)C_DIM);
  const float var  = s2 * (1.f / (float)C_DIM) - mu * mu;
  const float rsig = rsqrtf(var + 1e-5f);

#pragma unroll
  for (int j = 0; j < 3; ++j) {
    const int cc = tid + j * 256;
    float yv = (vals[j] - mu) * rsig * gam[cc] + bet[cc];
    go[cc] = f2bf(yv * bf2f(sr[cc]));
  }
}

// ---------------------------------------------------------------------------
extern "C" void kernel_launch(void* const* d_in, const int* in_sizes, int n_in,
                              void* d_out, int out_size, void* d_ws, size_t ws_size,
                              hipStream_t stream) {
  const float* x     = (const float*)d_in[0];
  const int*   sidx  = (const int*)  d_in[1];
  const float* decay = (const float*)d_in[2];
  const float* first = (const float*)d_in[3];
  const float* Wk    = (const float*)d_in[4];
  const float* Wv    = (const float*)d_in[5];
  const float* Wr    = (const float*)d_in[6];
  const float* Wo    = (const float*)d_in[7];
  const float* ln_g  = (const float*)d_in[8];
  const float* ln_b  = (const float*)d_in[9];
  float* out = (float*)d_out;

  const size_t NE = (size_t)M_ROWS * C_DIM;  // 25165824
  // Workspace layout (~210 MB, R10 aliasing):
  short* Whs  = (short*)d_ws;                        // 4*CC bf16 [Wk|Wv|Wr|Wo]
  short* x_hi = Whs + 4 * (size_t)CC;                // NE bf16
  unsigned short* Ybuf = (unsigned short*)x_hi;      // alias: Y after kvr done
  unsigned short* Kbuf = (unsigned short*)(x_hi + NE);  // NE bf16
  unsigned short* Gbuf = Kbuf;                       // alias: after K dead
  unsigned short* Vbuf = Kbuf + NE;                  // NE bf16
  unsigned short* SRb  = Vbuf + NE;                  // NE bf16
  float* aL = (float*)(SRb + NE);                    // 6 x 196608 f32
  float* bL = aL + 196608;
  float* pL = bL + 196608;
  float* aI = pL + 196608;
  float* bI = aI + 196608;
  float* pI = bI + 196608;

  // Allow 128 KB dynamic LDS (idempotent, capture-safe).
  (void)hipFuncSetAttribute(reinterpret_cast<const void*>(&gemmPF<0>),
                            hipFuncAttributeMaxDynamicSharedMemorySize, 131072);
  (void)hipFuncSetAttribute(reinterpret_cast<const void*>(&gemmPF<1>),
                            hipFuncAttributeMaxDynamicSharedMemorySize, 131072);

  // 1) bf16 conversions
  convert_x<<<24576, 256, 0, stream>>>((const float4*)x, (ushort4*)x_hi);
  convert_w4<<<dim3(576, 4), 256, 0, stream>>>(
      (const float4*)Wk, (const float4*)Wv, (const float4*)Wr, (const float4*)Wo,
      (ushort4*)Whs);

  // 2) fused k|v|sr GEMM: M=32768, N=2304, K=768; all outputs bf16
  gemmPF<0><<<dim3(9, 128), 512, 131072, stream>>>(
      x_hi, Whs, Kbuf, Vbuf, SRb, nullptr);

  // 3) WKV: chunk transitions -> serial chunk scan -> replay with y output
  wkv_pass1<<<dim3(NCH, 3, B_DIM), 256, 0, stream>>>(Kbuf, Vbuf, sidx, decay, aL, bL, pL);
  wkv_scan<<<24, 256, 0, stream>>>(aL, bL, pL, aI, bI, pI, decay);
  wkv_pass2<<<dim3(NCH, 3, B_DIM), 256, 0, stream>>>(Kbuf, Vbuf, sidx, decay, first,
                                                     aI, bI, pI, Ybuf);
  // 4) LayerNorm + gate -> bf16 GEMM operand (G aliases K; K dead now)
  ln_gate<<<M_ROWS, 256, 0, stream>>>(Ybuf, SRb, ln_g, ln_b, Gbuf);
  // 5) out = G @ Wo^T (384 blocks of 256^2, f32 out)
  gemmPF<1><<<dim3(3, 128), 512, 131072, stream>>>(
      (const short*)Gbuf, Whs + 3 * (size_t)CC, nullptr, nullptr, nullptr, out);
}

// Round 13
// 309.808 us; speedup vs baseline: 1.2271x; 1.0115x over previous
//
#include <hip/hip_runtime.h>
#include <cstddef>
#include <cstdint>

#define B_DIM 8
#define T_SEQ 4096
#define C_DIM 768
#define M_ROWS (B_DIM * T_SEQ)   // 32768
#define CC (C_DIM * C_DIM)       // 589824
#define NCH 32
#define CHL (T_SEQ / NCH)        // 128

using bf16x8 = __attribute__((ext_vector_type(8))) short;
using f32x4  = __attribute__((ext_vector_type(4))) float;

static __device__ __forceinline__ unsigned short f2bf(float f) {
  unsigned int u = __float_as_uint(f);
  return (unsigned short)((u + 0x7fffu + ((u >> 16) & 1u)) >> 16);
}
static __device__ __forceinline__ float bf2f(unsigned short s) {
  return __uint_as_float(((unsigned int)s) << 16);
}

static __device__ __forceinline__ void gload_lds16(const void* g, void* l) {
  __builtin_amdgcn_global_load_lds(
      (const __attribute__((address_space(1))) unsigned int*)g,
      (__attribute__((address_space(3))) unsigned int*)l, 16, 0, 0);
}

// ---------------------------------------------------------------------------
// f32 -> bf16 converts.
// ---------------------------------------------------------------------------
__global__ __launch_bounds__(256) void convert_x(
    const float4* __restrict__ x, ushort4* __restrict__ xh)
{
  int i = blockIdx.x * 256 + threadIdx.x;
  float4 v = x[i];
  ushort4 h;
  h.x = f2bf(v.x); h.y = f2bf(v.y); h.z = f2bf(v.z); h.w = f2bf(v.w);
  xh[i] = h;
}

__global__ __launch_bounds__(256) void convert_w4(
    const float4* __restrict__ w0, const float4* __restrict__ w1,
    const float4* __restrict__ w2, const float4* __restrict__ w3,
    ushort4* __restrict__ dst)
{
  const int z = blockIdx.y;
  const float4* __restrict__ src = (z == 0) ? w0 : (z == 1) ? w1 : (z == 2) ? w2 : w3;
  int i = blockIdx.x * 256 + threadIdx.x;
  float4 v = src[i];
  ushort4 h;
  h.x = f2bf(v.x); h.y = f2bf(v.y); h.z = f2bf(v.z); h.w = f2bf(v.w);
  dst[(size_t)z * (CC / 4) + i] = h;
}

// ---------------------------------------------------------------------------
// 2-blocks/CU MFMA GEMM (NT), K=768, tile 256x128, BK=32, 256 threads
// (4 waves, 2M x 2N), per-wave 128x64 out (acc 8x4 — same per-wave shape
// as the 141us kernel). LDS 72KB = 3 rotating regions x 24KB (A 16KB +
// B 8KB) -> 2 blocks/CU: co-resident block hides barrier/drain stalls.
// Region r staged at phase r-2 (6 gloads/thread), drained by vmcnt(6)
// after MM (2-phase DMA window), ONE barrier per phase. Sector-coalesced
// staging: 4 lanes/row, 64B contiguous per row; chunk slot = kq ^
// ((row>>1)&3), inverse applied on global source (both-sides rule).
// Frag reads direct (3-region rotation precludes reg-prefetch; R11 showed
// prefetch worth only ~4%).
// MODE 0: fused kvr, N=2304 over [Wk|Wv|Wr]; bf16 outs K/V/sigmoid->SR.
// MODE 1: out-GEMM, N=768, f32 out.
// ---------------------------------------------------------------------------
#define STG3(R) do { if ((R) < 24) {                                       \
    const int rbs_ = ((R) % 3) * 12288;  /* shorts */                      \
    const int ko_ = (R) * 32;                                              \
    short* da_ = lds + rbs_ + wave * 512;                                  \
    gload_lds16(pAs + ko_, da_);                                           \
    gload_lds16(pAs +  64 * 768 + ko_, da_ + 2048);                        \
    gload_lds16(pAs + 128 * 768 + ko_, da_ + 4096);                        \
    gload_lds16(pAs + 192 * 768 + ko_, da_ + 6144);                        \
    short* db_ = lds + rbs_ + 8192 + wave * 512;                           \
    gload_lds16(pBs + ko_, db_);                                           \
    gload_lds16(pBs +  64 * 768 + ko_, db_ + 2048);                        \
  } } while (0)

#define RDF(R) do {                                                        \
    const int rb_ = ((R) % 3) * 24576;  /* bytes */                        \
    _Pragma("unroll")                                                      \
    for (int mi = 0; mi < 8; ++mi)                                         \
      a[mi] = *(const bf16x8*)(lds + ((rb_ + abase + mi * 1024) >> 1));    \
    _Pragma("unroll")                                                      \
    for (int ni = 0; ni < 4; ++ni)                                         \
      b[ni] = *(const bf16x8*)(lds + ((rb_ + bbase + ni * 1024) >> 1));    \
  } while (0)

#define MM()                                                               \
    _Pragma("unroll")                                                      \
    for (int mi = 0; mi < 8; ++mi)                                         \
      _Pragma("unroll")                                                    \
      for (int ni = 0; ni < 4; ++ni)                                       \
        acc[mi][ni] = __builtin_amdgcn_mfma_f32_16x16x32_bf16(             \
            a[mi], b[ni], acc[mi][ni], 0, 0, 0);

#define PH3(P)                                                             \
  {                                                                        \
    RDF(P);                                                                \
    STG3((P) + 2);                                                         \
    __builtin_amdgcn_sched_barrier(0);                                     \
    __builtin_amdgcn_s_setprio(1);                                         \
    MM()                                                                   \
    __builtin_amdgcn_s_setprio(0);                                         \
    if ((P) <= 21)      { asm volatile("s_waitcnt vmcnt(6)" ::: "memory"); } \
    else if ((P) == 22) { asm volatile("s_waitcnt vmcnt(0)" ::: "memory"); } \
    __builtin_amdgcn_s_barrier();                                          \
    __builtin_amdgcn_sched_barrier(0);                                     \
  }

template<int MODE>
__global__ __launch_bounds__(256, 2) void gemmDB(
    const short* __restrict__ A, const short* __restrict__ Wb,
    unsigned short* __restrict__ OK, unsigned short* __restrict__ OV,
    unsigned short* __restrict__ OSR, float* __restrict__ Oout)
{
  extern __shared__ short lds[];   // 72 KB
  const int K = C_DIM;
  constexpr int NWN = (MODE == 0) ? 18 : 6;    // n-tiles of 128
  constexpr int CPX = (MODE == 0) ? 288 : 96;  // blocks per XCD (bijective)

  int f  = blockIdx.x + blockIdx.y * NWN;
  int wg = (f & 7) * CPX + (f >> 3);
  const int n0 = (wg % NWN) * 128;
  const int m0 = (wg / NWN) * 256;

  const int tid  = threadIdx.x;
  const int lane = tid & 63, wave = tid >> 6;
  const int wr = wave >> 1, wc = wave & 1;   // 2M x 2N wave grid
  const int lr = lane & 15, lk = lane >> 4;

  // fragment swizzle (lane-constant): slot = lk ^ ((lr>>1)&3)
  const int aswz = lk ^ ((lr >> 1) & 3);
  const int abase = (wr * 128 + lr) * 64 + aswz * 16;           // bytes
  const int bbase = 16384 + (wc * 64 + lr) * 64 + aswz * 16;    // bytes

  // staging sources: 4 lanes/row, 64B/row (chunk-permuted).
  const int srow = tid >> 2;                          // 0..63
  const int skq  = (tid & 3) ^ ((tid >> 3) & 3);
  const short* pAs = A  + (size_t)(m0 + srow) * K + skq * 8;
  const short* pBs = Wb + (size_t)(n0 + srow) * K + skq * 8;

  f32x4 acc[8][4];
#pragma unroll
  for (int i = 0; i < 8; ++i)
#pragma unroll
    for (int j = 0; j < 4; ++j) acc[i][j] = (f32x4){0.f, 0.f, 0.f, 0.f};

  bf16x8 a[8], b[4];

  // Prologue: stage regions 0,1; drain r0 (leave r1 in flight); barrier.
  STG3(0); STG3(1);
  asm volatile("s_waitcnt vmcnt(6)" ::: "memory");
  __builtin_amdgcn_s_barrier();
  __builtin_amdgcn_sched_barrier(0);

  // 24 phases, one BK=32 K-tile each.
#pragma unroll
  for (int p = 0; p < 24; ++p) PH3(p)

  // Epilogue
  if (MODE == 0) {
    const int which = n0 / 768;               // 0:K 1:V 2:SR (all bf16 out)
    const int nc = (n0 % 768) + wc * 64;
    unsigned short* __restrict__ D = (which == 0) ? OK : (which == 1) ? OV : OSR;
#pragma unroll
    for (int mi = 0; mi < 8; ++mi)
#pragma unroll
      for (int ni = 0; ni < 4; ++ni) {
        const int row = m0 + wr * 128 + mi * 16 + lk * 4;
        const int col = nc + ni * 16 + lr;
#pragma unroll
        for (int j = 0; j < 4; ++j) {
          float v = acc[mi][ni][j];
          if (which == 2) v = 1.f / (1.f + __expf(-v));
          D[(size_t)(row + j) * C_DIM + col] = f2bf(v);
        }
      }
  } else {
#pragma unroll
    for (int mi = 0; mi < 8; ++mi)
#pragma unroll
      for (int ni = 0; ni < 4; ++ni) {
        const int row = m0 + wr * 128 + mi * 16 + lk * 4;
        const int col = n0 + wc * 64 + ni * 16 + lr;
#pragma unroll
        for (int j = 0; j < 4; ++j)
          Oout[(size_t)(row + j) * C_DIM + col] = acc[mi][ni][j];
      }
  }
}

// ---------------------------------------------------------------------------
// WKV chunk-parallel scan over bf16 K/V (R9/R10 proven versions).
// ---------------------------------------------------------------------------
#define P1_LOAD(kk_, vv_, base_)                                  \
  _Pragma("unroll") for (int j = 0; j < 8; ++j) {                 \
    int r_ = si[(base_) + j];                                     \
    kk_[j] = Kb[(size_t)r_ * C_DIM];                              \
    vv_[j] = Vb[(size_t)r_ * C_DIM];                              \
  }
#define P1_COMP(kk_, vv_)                                         \
  _Pragma("unroll") for (int j = 0; j < 8; ++j) {                 \
    float kt = bf2f(kk_[j]), vt = bf2f(vv_[j]);                   \
    float ww2 = w + pp; float p2 = fmaxf(ww2, kt);                \
    float e1b = __expf(ww2 - p2), e2b = __expf(kt - p2);          \
    aa = e1b * aa + e2b * vt; bb = e1b * bb + e2b; pp = p2;       \
  }

__global__ __launch_bounds__(256) void wkv_pass1(
    const unsigned short* __restrict__ Kin, const unsigned short* __restrict__ Vin,
    const int* __restrict__ sidx, const float* __restrict__ decay,
    float* __restrict__ aL, float* __restrict__ bL, float* __restrict__ pL)
{
  __shared__ int si[CHL];
  const int tid = threadIdx.x;
  const int ch = blockIdx.x, b = blockIdx.z;
  const int c = blockIdx.y * 256 + tid;
  if (tid < CHL) si[tid] = sidx[ch * CHL + tid];
  __syncthreads();
  const float w = decay[c] * (1.0f / (float)T_SEQ);
  const unsigned short* Kb = Kin + (size_t)b * T_SEQ * C_DIM + c;
  const unsigned short* Vb = Vin + (size_t)b * T_SEQ * C_DIM + c;
  float aa = 0.f, bb = 0.f, pp = -1e38f;
  unsigned short kA[8], vA[8], kB[8], vB[8];
  P1_LOAD(kA, vA, 0)
  for (int t0 = 0; t0 < CHL; t0 += 16) {
    P1_LOAD(kB, vB, t0 + 8)
    P1_COMP(kA, vA)
    if (t0 + 16 < CHL) { P1_LOAD(kA, vA, t0 + 16) }
    P1_COMP(kB, vB)
  }
  const int idx = (b * C_DIM + c) * NCH + ch;
  aL[idx] = aa; bL[idx] = bb; pL[idx] = pp;
}

// Serial scan over chunks per (b,c).
__global__ __launch_bounds__(256) void wkv_scan(
    const float* __restrict__ aL, const float* __restrict__ bL,
    const float* __restrict__ pL,
    float* __restrict__ aI, float* __restrict__ bI, float* __restrict__ pI,
    const float* __restrict__ decay)
{
  const int g = blockIdx.x * 256 + threadIdx.x;  // 0..6143 = b*C + c
  const int c = g % C_DIM;
  const float wL = decay[c] * ((float)CHL / (float)T_SEQ);
  float aa = 0.f, bb = 0.f, pp = -1e38f;
  const int base = g * NCH;
  for (int ch = 0; ch < NCH; ++ch) {
    aI[base + ch] = aa; bI[base + ch] = bb; pI[base + ch] = pp;
    float p1 = pp + wL;
    float p2 = pL[base + ch];
    float p  = fmaxf(p1, p2);
    float e1 = __expf(p1 - p), e2 = __expf(p2 - p);
    aa = e1 * aa + e2 * aL[base + ch];
    bb = e1 * bb + e2 * bL[base + ch];
    pp = p;
  }
}

// Pass 2: replay chunk with incoming state; y (bf16) scattered to natural order.
#define P2_LOAD(rr_, kk_, vv_, base_)                             \
  _Pragma("unroll") for (int j = 0; j < 8; ++j) {                 \
    int r_ = si[(base_) + j];                                     \
    rr_[j] = r_;                                                  \
    kk_[j] = Kb[(size_t)r_ * C_DIM];                              \
    vv_[j] = Vb[(size_t)r_ * C_DIM];                              \
  }
#define P2_COMP(rr_, kk_, vv_)                                    \
  _Pragma("unroll") for (int j = 0; j < 8; ++j) {                 \
    float kt = bf2f(kk_[j]), vt = bf2f(vv_[j]);                   \
    float ww = u + kt; float p = fmaxf(pp, ww);                   \
    float e1 = __expf(pp - p), e2 = __expf(ww - p);               \
    float y = (e1 * aa + e2 * vt) / (e1 * bb + e2);               \
    Yb[(size_t)rr_[j] * C_DIM] = f2bf(y);                         \
    float ww2 = w + pp; float p2 = fmaxf(ww2, kt);                \
    float e1b = __expf(ww2 - p2), e2b = __expf(kt - p2);          \
    aa = e1b * aa + e2b * vt; bb = e1b * bb + e2b; pp = p2;       \
  }

__global__ __launch_bounds__(256) void wkv_pass2(
    const unsigned short* __restrict__ Kin, const unsigned short* __restrict__ Vin,
    const int* __restrict__ sidx,
    const float* __restrict__ decay, const float* __restrict__ first,
    const float* __restrict__ aI, const float* __restrict__ bI,
    const float* __restrict__ pI, unsigned short* __restrict__ Y)
{
  __shared__ int si[CHL];
  const int tid = threadIdx.x;
  const int ch = blockIdx.x, b = blockIdx.z;
  const int c = blockIdx.y * 256 + tid;
  if (tid < CHL) si[tid] = sidx[ch * CHL + tid];
  __syncthreads();
  const float w = decay[c] * (1.0f / (float)T_SEQ);
  const float u = first[c] * (1.0f / (float)T_SEQ);
  const unsigned short* Kb = Kin + (size_t)b * T_SEQ * C_DIM + c;
  const unsigned short* Vb = Vin + (size_t)b * T_SEQ * C_DIM + c;
  unsigned short* Yb = Y + (size_t)b * T_SEQ * C_DIM + c;
  const int idx = (b * C_DIM + c) * NCH + ch;
  float aa = aI[idx], bb = bI[idx], pp = pI[idx];
  int rA[8], rB[8]; unsigned short kA[8], vA[8], kB[8], vB[8];
  P2_LOAD(rA, kA, vA, 0)
  for (int t0 = 0; t0 < CHL; t0 += 16) {
    P2_LOAD(rB, kB, vB, t0 + 8)
    P2_COMP(rA, kA, vA)
    if (t0 + 16 < CHL) { P2_LOAD(rA, kA, vA, t0 + 16) }
    P2_COMP(rB, kB, vB)
  }
}

// ---------------------------------------------------------------------------
// Row LayerNorm over C + sigmoid gate; bf16 in (Y, SR), bf16 out (G).
// ---------------------------------------------------------------------------
__global__ __launch_bounds__(256) void ln_gate(
    const unsigned short* __restrict__ Y, const unsigned short* __restrict__ SR,
    const float* __restrict__ gam, const float* __restrict__ bet,
    unsigned short* __restrict__ G)
{
  const size_t row = blockIdx.x;
  const unsigned short* x = Y + row * C_DIM;
  const unsigned short* sr = SR + row * C_DIM;
  unsigned short* go = G + row * C_DIM;
  const int tid = threadIdx.x;

  float vals[3];
  float s = 0.f, s2 = 0.f;
#pragma unroll
  for (int j = 0; j < 3; ++j) {
    float v = bf2f(x[tid + j * 256]);
    vals[j] = v;
    s += v; s2 += v * v;
  }
#pragma unroll
  for (int off = 32; off >= 1; off >>= 1) {
    s  += __shfl_xor(s, off, 64);
    s2 += __shfl_xor(s2, off, 64);
  }
  __shared__ float red[8];
  const int wid = tid >> 6;
  if ((tid & 63) == 0) { red[wid] = s; red[wid + 4] = s2; }
  __syncthreads();
  s  = red[0] + red[1] + red[2] + red[3];
  s2 = red[4] + red[5] + red[6] + red[7];

  const float mu   = s * (1.f / (float)C_DIM);
  const float var  = s2 * (1.f / (float)C_DIM) - mu * mu;
  const float rsig = rsqrtf(var + 1e-5f);

#pragma unroll
  for (int j = 0; j < 3; ++j) {
    const int cc = tid + j * 256;
    float yv = (vals[j] - mu) * rsig * gam[cc] + bet[cc];
    go[cc] = f2bf(yv * bf2f(sr[cc]));
  }
}

// ---------------------------------------------------------------------------
extern "C" void kernel_launch(void* const* d_in, const int* in_sizes, int n_in,
                              void* d_out, int out_size, void* d_ws, size_t ws_size,
                              hipStream_t stream) {
  const float* x     = (const float*)d_in[0];
  const int*   sidx  = (const int*)  d_in[1];
  const float* decay = (const float*)d_in[2];
  const float* first = (const float*)d_in[3];
  const float* Wk    = (const float*)d_in[4];
  const float* Wv    = (const float*)d_in[5];
  const float* Wr    = (const float*)d_in[6];
  const float* Wo    = (const float*)d_in[7];
  const float* ln_g  = (const float*)d_in[8];
  const float* ln_b  = (const float*)d_in[9];
  float* out = (float*)d_out;

  const size_t NE = (size_t)M_ROWS * C_DIM;  // 25165824
  // Workspace layout (~210 MB, R10 aliasing):
  short* Whs  = (short*)d_ws;                        // 4*CC bf16 [Wk|Wv|Wr|Wo]
  short* x_hi = Whs + 4 * (size_t)CC;                // NE bf16
  unsigned short* Ybuf = (unsigned short*)x_hi;      // alias: Y after kvr done
  unsigned short* Kbuf = (unsigned short*)(x_hi + NE);  // NE bf16
  unsigned short* Gbuf = Kbuf;                       // alias: after K dead
  unsigned short* Vbuf = Kbuf + NE;                  // NE bf16
  unsigned short* SRb  = Vbuf + NE;                  // NE bf16
  float* aL = (float*)(SRb + NE);                    // 6 x 196608 f32
  float* bL = aL + 196608;
  float* pL = bL + 196608;
  float* aI = pL + 196608;
  float* bI = aI + 196608;
  float* pI = bI + 196608;

  // Allow 72 KB dynamic LDS (idempotent, capture-safe).
  (void)hipFuncSetAttribute(reinterpret_cast<const void*>(&gemmDB<0>),
                            hipFuncAttributeMaxDynamicSharedMemorySize, 73728);
  (void)hipFuncSetAttribute(reinterpret_cast<const void*>(&gemmDB<1>),
                            hipFuncAttributeMaxDynamicSharedMemorySize, 73728);

  // 1) bf16 conversions
  convert_x<<<24576, 256, 0, stream>>>((const float4*)x, (ushort4*)x_hi);
  convert_w4<<<dim3(576, 4), 256, 0, stream>>>(
      (const float4*)Wk, (const float4*)Wv, (const float4*)Wr, (const float4*)Wo,
      (ushort4*)Whs);

  // 2) fused k|v|sr GEMM: M=32768, N=2304, K=768 (2304 blocks of 256x128)
  gemmDB<0><<<dim3(18, 128), 256, 73728, stream>>>(
      x_hi, Whs, Kbuf, Vbuf, SRb, nullptr);

  // 3) WKV: chunk transitions -> serial chunk scan -> replay with y output
  wkv_pass1<<<dim3(NCH, 3, B_DIM), 256, 0, stream>>>(Kbuf, Vbuf, sidx, decay, aL, bL, pL);
  wkv_scan<<<24, 256, 0, stream>>>(aL, bL, pL, aI, bI, pI, decay);
  wkv_pass2<<<dim3(NCH, 3, B_DIM), 256, 0, stream>>>(Kbuf, Vbuf, sidx, decay, first,
                                                     aI, bI, pI, Ybuf);
  // 4) LayerNorm + gate -> bf16 GEMM operand (G aliases K; K dead now)
  ln_gate<<<M_ROWS, 256, 0, stream>>>(Ybuf, SRb, ln_g, ln_b, Gbuf);
  // 5) out = G @ Wo^T (768 blocks of 256x128, f32 out)
  gemmDB<1><<<dim3(6, 128), 256, 73728, stream>>>(
      (const short*)Gbuf, Whs + 3 * (size_t)CC, nullptr, nullptr, nullptr, out);
}